// Round 1
// baseline (4175.002 us; speedup 1.0000x reference)
//
#include <hip/hip_runtime.h>
#include <math.h>

#define N_NODES 30000
#define N_EDGES 400000
#define BANK_PAD 4

// ---------- float atomic max via int/uint atomics (valid incl. -inf init) ----
__device__ __forceinline__ void atomic_max_f(float* addr, float v) {
    if (v >= 0.0f) {
        atomicMax((int*)addr, __float_as_int(v));
    } else {
        atomicMin((unsigned int*)addr, __float_as_uint(v));
    }
}

__global__ __launch_bounds__(256) void fill_neg_inf(float* p, int n) {
    int i = blockIdx.x * blockDim.x + threadIdx.x;
    int stride = gridDim.x * blockDim.x;
    for (; i < n; i += stride) p[i] = -INFINITY;
}

// ---------- A[n][COUT] = fixup(feat[n][K]) @ wa[0:K][COUT] + b  --------------
// fixup: non-finite (−inf from empty segment_max) -> 0, matching jnp.where(isfinite)
template<int K, int COUT>
__global__ __launch_bounds__(256) void node_linear(const float* __restrict__ feat,
                                                   const float* __restrict__ wa,
                                                   const float* __restrict__ b,
                                                   float* __restrict__ A) {
    constexpr int NPB = 8;            // nodes per block
    constexpr int G   = 256 / COUT;   // parallel node groups
    constexpr int NPT = NPB / G;      // nodes per thread
    __shared__ float sf[NPB * K];
    const int node0 = blockIdx.x * NPB;
    for (int idx = threadIdx.x; idx < NPB * K; idx += 256) {
        float v = feat[node0 * K + idx];
        if (!isfinite(v)) v = 0.0f;
        sf[idx] = v;
    }
    __syncthreads();
    const int j  = threadIdx.x % COUT;
    const int g  = threadIdx.x / COUT;
    const int n0 = g * NPT;
    float acc[NPT];
#pragma unroll
    for (int i = 0; i < NPT; i++) acc[i] = 0.0f;
    for (int k = 0; k < K; k++) {
        float w = wa[k * COUT + j];
#pragma unroll
        for (int nn = 0; nn < NPT; nn++)
            acc[nn] = fmaf(sf[(n0 + nn) * K + k], w, acc[nn]);
    }
    const float bj = b[j];
#pragma unroll
    for (int nn = 0; nn < NPT; nn++)
        A[(size_t)(node0 + n0 + nn) * COUT + j] = acc[nn] + bj;
}

// ---------- per-edge:  h1 = relu(A[src] + rel @ wa_rel); msg = h1 @ wb + bb;
//            atomic segment-max(msg) into agg[dst]  -------------------------
// TE chosen so TE*COUT == 8192  ->  8 edges x 4 cols per thread in phase 2.
template<int COUT, int TE>
__global__ __launch_bounds__(256) void edge_mlp(const float* __restrict__ A,
                                                const float* __restrict__ warel, // 3 x COUT
                                                const float* __restrict__ wb,    // COUT x COUT
                                                const float* __restrict__ bb,
                                                const float* __restrict__ pos,
                                                const int* __restrict__ src,
                                                const int* __restrict__ dst,
                                                float* __restrict__ agg) {
    constexpr int STRIDE = TE + BANK_PAD;       // keeps rows 16B-aligned, breaks bank stride
    constexpr int CT  = COUT / 4;               // column tiles
    constexpr int EG  = 256 / CT;               // edge groups
    constexpr int EPT = TE / EG;                // edges per thread (== 8)
    static_assert(EPT == 8, "tile mismatch");

    __shared__ __align__(16) float h1T[COUT * STRIDE];  // h1 transposed: [k][e]
    __shared__ float s_rx[TE], s_ry[TE], s_rz[TE];
    __shared__ int   s_src[TE], s_dst[TE];

    const int tid = threadIdx.x;
    const int e_base = blockIdx.x * TE;
    if (tid < TE) {
        int s = src[e_base + tid];
        int d = dst[e_base + tid];
        s_src[tid] = s;  s_dst[tid] = d;
        s_rx[tid] = pos[3 * s + 0] - pos[3 * d + 0];
        s_ry[tid] = pos[3 * s + 1] - pos[3 * d + 1];
        s_rz[tid] = pos[3 * s + 2] - pos[3 * d + 2];
    }
    __syncthreads();

    // phase 1: h1T[j][e] = relu(A[src[e]][j] + rel . warel[:,j])   (A already has +ba)
    for (int idx = tid; idx < TE * COUT; idx += 256) {
        int j = idx % COUT;      // fast -> coalesced A reads
        int e = idx / COUT;
        float v = A[(size_t)s_src[e] * COUT + j]
                + s_rx[e] * warel[j]
                + s_ry[e] * warel[COUT + j]
                + s_rz[e] * warel[2 * COUT + j];
        h1T[j * STRIDE + e] = fmaxf(v, 0.0f);
    }
    __syncthreads();

    // phase 2: msg[e][j] = sum_k h1[e][k] * wb[k][j]   (8 edges x 4 cols per thread)
    const int jt = tid % CT, j0 = jt * 4;
    const int eg = tid / CT, e0 = eg * EPT;
    float acc[8][4];
#pragma unroll
    for (int i = 0; i < 8; i++) { acc[i][0] = acc[i][1] = acc[i][2] = acc[i][3] = 0.0f; }

    for (int k = 0; k < COUT; k++) {
        float4 w = *(const float4*)(wb + (size_t)k * COUT + j0);
        const float* hr = &h1T[k * STRIDE + e0];
        float4 ha = *(const float4*)(hr);
        float4 hb = *(const float4*)(hr + 4);
        float h[8] = {ha.x, ha.y, ha.z, ha.w, hb.x, hb.y, hb.z, hb.w};
#pragma unroll
        for (int ee = 0; ee < 8; ee++) {
            acc[ee][0] = fmaf(h[ee], w.x, acc[ee][0]);
            acc[ee][1] = fmaf(h[ee], w.y, acc[ee][1]);
            acc[ee][2] = fmaf(h[ee], w.z, acc[ee][2]);
            acc[ee][3] = fmaf(h[ee], w.w, acc[ee][3]);
        }
    }

    float4 bv = *(const float4*)(bb + j0);
#pragma unroll
    for (int ee = 0; ee < 8; ee++) {
        int d = s_dst[e0 + ee];
        float* base = agg + (size_t)d * COUT + j0;
        atomic_max_f(base + 0, acc[ee][0] + bv.x);
        atomic_max_f(base + 1, acc[ee][1] + bv.y);
        atomic_max_f(base + 2, acc[ee][2] + bv.z);
        atomic_max_f(base + 3, acc[ee][3] + bv.w);
    }
}

// ---------- projection: scatter-add features into (B,256,60,80) --------------
__global__ __launch_bounds__(256) void project(const float* __restrict__ feat, // N x 256
                                               const float* __restrict__ pos,
                                               const float* __restrict__ Km,
                                               const int* __restrict__ batch,
                                               float* __restrict__ out) {
    const int n = blockIdx.x;
    const float X = pos[3 * n + 0], Y = pos[3 * n + 1], Z = pos[3 * n + 2];
    const float k00 = Km[0], k02 = Km[2], k11 = Km[4], k12 = Km[5];
    const int u = (int)((k00 * X / Z + k02) / 640.0f * 80.0f);   // trunc-toward-zero == astype(int32)
    const int v = (int)((k11 * Y / Z + k12) / 480.0f * 60.0f);
    if (u < 0 || u >= 80 || v < 0 || v >= 60) return;
    const int b = batch[n];
    const int c = threadIdx.x;
    float val = feat[(size_t)n * 256 + c];
    if (!isfinite(val)) val = 0.0f;
    atomicAdd(out + (((size_t)b * 256 + c) * 60 + v) * 80 + u, val);
}

// ---------------------------------------------------------------------------
extern "C" void kernel_launch(void* const* d_in, const int* in_sizes, int n_in,
                              void* d_out, int out_size, void* d_ws, size_t ws_size,
                              hipStream_t stream) {
    const float* x   = (const float*)d_in[0];
    const float* pos = (const float*)d_in[1];
    const float* Km  = (const float*)d_in[2];
    const float* w11 = (const float*)d_in[3];
    const float* b11 = (const float*)d_in[4];
    const float* w12 = (const float*)d_in[5];
    const float* b12 = (const float*)d_in[6];
    const float* w21 = (const float*)d_in[7];
    const float* b21 = (const float*)d_in[8];
    const float* w22 = (const float*)d_in[9];
    const float* b22 = (const float*)d_in[10];
    const float* w31 = (const float*)d_in[11];
    const float* b31 = (const float*)d_in[12];
    const float* w32 = (const float*)d_in[13];
    const float* b32 = (const float*)d_in[14];
    const int* edge  = (const int*)d_in[15];
    const int* batch = (const int*)d_in[16];
    const int* srcp = edge;
    const int* dstp = edge + N_EDGES;
    float* out = (float*)d_out;

    float* featA = (float*)d_ws;                      // N x 256
    float* featB = featA + (size_t)N_NODES * 256;     // N x 256
    float* Abuf  = featB + (size_t)N_NODES * 256;     // N x 256

    // ---- layer 1: cin=16, cout=64
    node_linear<16, 64><<<N_NODES / 8, 256, 0, stream>>>(x, w11, b11, Abuf);
    fill_neg_inf<<<512, 256, 0, stream>>>(featB, N_NODES * 64);
    edge_mlp<64, 128><<<N_EDGES / 128, 256, 0, stream>>>(Abuf, w11 + 16 * 64, w12, b12,
                                                         pos, srcp, dstp, featB);
    // ---- layer 2: cin=64, cout=128
    node_linear<64, 128><<<N_NODES / 8, 256, 0, stream>>>(featB, w21, b21, Abuf);
    fill_neg_inf<<<512, 256, 0, stream>>>(featA, N_NODES * 128);
    edge_mlp<128, 64><<<N_EDGES / 64, 256, 0, stream>>>(Abuf, w21 + 64 * 128, w22, b22,
                                                        pos, srcp, dstp, featA);
    // ---- layer 3: cin=128, cout=256
    node_linear<128, 256><<<N_NODES / 8, 256, 0, stream>>>(featA, w31, b31, Abuf);
    fill_neg_inf<<<512, 256, 0, stream>>>(featB, N_NODES * 256);
    edge_mlp<256, 32><<<N_EDGES / 32, 256, 0, stream>>>(Abuf, w31 + 128 * 256, w32, b32,
                                                        pos, srcp, dstp, featB);
    // ---- projection
    hipMemsetAsync(d_out, 0, (size_t)out_size * sizeof(float), stream);
    project<<<N_NODES, 256, 0, stream>>>(featB, pos, Km, batch, out);
}

// Round 2
// 785.031 us; speedup vs baseline: 5.3183x; 5.3183x over previous
//
#include <hip/hip_runtime.h>
#include <math.h>

#define NN 30000
#define NE 400000

typedef _Float16 f16;
typedef _Float16 f16x8 __attribute__((ext_vector_type(8)));
typedef float f32x4 __attribute__((ext_vector_type(4)));

// ---------- float atomic max via int/uint atomics (valid incl. -inf init) ----
__device__ __forceinline__ void atomic_max_f(float* addr, float v) {
    if (v >= 0.0f) {
        atomicMax((int*)addr, __float_as_int(v));
    } else {
        atomicMin((unsigned int*)addr, __float_as_uint(v));
    }
}

__global__ __launch_bounds__(256) void fill_neg_inf(float* p, int n) {
    int i = blockIdx.x * blockDim.x + threadIdx.x;
    int stride = gridDim.x * blockDim.x;
    for (; i < n; i += stride) p[i] = -INFINITY;
}

// ---------- counting-sort of edges by dst --------------------------------
__global__ __launch_bounds__(256) void hist_dst(const int* __restrict__ dst,
                                                int* __restrict__ counts) {
    int e = blockIdx.x * 256 + threadIdx.x;
    if (e < NE) atomicAdd(&counts[dst[e]], 1);
}

__global__ __launch_bounds__(1024) void scan_counts(const int* __restrict__ counts,
                                                    int* __restrict__ cursor) {
    __shared__ int lsum[1024];
    const int t = threadIdx.x;
    const int base = t * 30;                 // 1024*30 = 30720 >= 30000
    int s = 0;
    for (int i = 0; i < 30; ++i) {
        int idx = base + i;
        if (idx < NN) s += counts[idx];
    }
    lsum[t] = s;
    __syncthreads();
    int acc = s;
    for (int off = 1; off < 1024; off <<= 1) {
        int v = (t >= off) ? lsum[t - off] : 0;
        __syncthreads();
        acc += v;
        lsum[t] = acc;
        __syncthreads();
    }
    int run = acc - s;                       // exclusive prefix
    for (int i = 0; i < 30; ++i) {
        int idx = base + i;
        if (idx < NN) { cursor[idx] = run; run += counts[idx]; }
    }
}

__global__ __launch_bounds__(256) void scatter_edges(const int* __restrict__ src,
                                                     const int* __restrict__ dst,
                                                     int* __restrict__ cursor,
                                                     int* __restrict__ srcS,
                                                     int* __restrict__ dstS) {
    int e = blockIdx.x * 256 + threadIdx.x;
    if (e >= NE) return;
    int d = dst[e];
    int p = atomicAdd(&cursor[d], 1);
    srcS[p] = src[e];
    dstS[p] = d;
}

// ---------- pack wb (fp32 row-major KxN) into MFMA b-frag order, f16 ---------
// flat = ((nt*(C/32)+ks)*64 + lane)*8 + j ; k = ks*32 + (lane>>4)*8 + j ; n = nt*16 + (lane&15)
template<int C>
__global__ __launch_bounds__(256) void pack_wb(const float* __restrict__ wb,
                                               f16* __restrict__ pB) {
    int f = blockIdx.x * 256 + threadIdx.x;
    if (f >= C * C) return;
    int j = f & 7;
    int l = (f >> 3) & 63;
    int rest = f >> 9;
    constexpr int KS = C / 32;
    int ks = rest % KS;
    int nt = rest / KS;
    int k = ks * 32 + ((l >> 4) << 3) + j;
    int n = nt * 16 + (l & 15);
    pB[f] = (f16)wb[k * C + n];
}

// ---------- A[n][C] = fixup(feat[n][K]) @ wa[0:K][C] + b  -> f16 -------------
template<int K, int COUT>
__global__ __launch_bounds__(256) void node_linear(const float* __restrict__ feat,
                                                   const float* __restrict__ wa,
                                                   const float* __restrict__ b,
                                                   f16* __restrict__ A) {
    constexpr int NPB = 8;
    constexpr int G   = 256 / COUT;
    constexpr int NPT = NPB / G;
    __shared__ float sf[NPB * K];
    const int node0 = blockIdx.x * NPB;
    for (int idx = threadIdx.x; idx < NPB * K; idx += 256) {
        float v = feat[node0 * K + idx];
        if (!isfinite(v)) v = 0.0f;
        sf[idx] = v;
    }
    __syncthreads();
    const int j  = threadIdx.x % COUT;
    const int g  = threadIdx.x / COUT;
    const int n0 = g * NPT;
    float acc[NPT];
#pragma unroll
    for (int i = 0; i < NPT; i++) acc[i] = 0.0f;
    for (int k = 0; k < K; k++) {
        float w = wa[k * COUT + j];
#pragma unroll
        for (int nn = 0; nn < NPT; nn++)
            acc[nn] = fmaf(sf[(n0 + nn) * K + k], w, acc[nn]);
    }
    const float bj = b[j];
#pragma unroll
    for (int nn = 0; nn < NPT; nn++)
        A[(size_t)(node0 + n0 + nn) * COUT + j] = (f16)(acc[nn] + bj);
}

// ---------- edge kernel: h1=relu(Ah[src]+rel@warel) ; msg=h1@wb ;
//            in-LDS segmented max over dst-sorted edges ; atomic_max(+bb) -----
template<int C>
__global__ __launch_bounds__(256) void edge_mfma(const f16* __restrict__ Ah,
                                                 const float* __restrict__ warel, // 3 x C fp32
                                                 const f16* __restrict__ pB,      // packed
                                                 const float* __restrict__ bb,
                                                 const float* __restrict__ pos,
                                                 const int* __restrict__ srcS,
                                                 const int* __restrict__ dstS,
                                                 float* __restrict__ agg) {
    constexpr int TE  = 64;
    constexpr int NTW = C / 64;   // n-tiles per wave
    constexpr int KS  = C / 32;   // k-steps
    // smem: phase1/2 = h1 f16 [TE][C] (XOR-swizzled); phase3/4 = msg f32 [32][C]
    __shared__ __align__(16) unsigned char smem[TE * C * 2];
    __shared__ float s_warel[3 * C];
    __shared__ float s_rx[TE], s_ry[TE], s_rz[TE];
    __shared__ int s_src[TE], s_dst[TE];

    const int tid = threadIdx.x;
    // bijective XCD-aware swizzle (contiguous chunk per XCD)
    const int nwg = gridDim.x;
    const int q = nwg >> 3, r = nwg & 7;
    const int xcd = blockIdx.x & 7, o = blockIdx.x >> 3;
    const int bid = (xcd < r ? xcd * (q + 1) : r * (q + 1) + (xcd - r) * q) + o;
    const int e0 = bid * TE;

    if (tid < TE) {
        int s = srcS[e0 + tid], d = dstS[e0 + tid];
        s_src[tid] = s; s_dst[tid] = d;
        s_rx[tid] = pos[3 * s + 0] - pos[3 * d + 0];
        s_ry[tid] = pos[3 * s + 1] - pos[3 * d + 1];
        s_rz[tid] = pos[3 * s + 2] - pos[3 * d + 2];
    }
    for (int i = tid; i < 3 * C; i += 256) s_warel[i] = warel[i];
    __syncthreads();

    // ---- phase 1: h1 into LDS (f16, XOR-swizzled rows)
    {
        const int e = tid >> 2, p = tid & 3;
        const int s = s_src[e];
        const float rx = s_rx[e], ry = s_ry[e], rz = s_rz[e];
        const f16* arow = Ah + (size_t)s * C;
#pragma unroll
        for (int ch = 0; ch < C / 32; ++ch) {
            const int j0 = (ch * 4 + p) * 8;
            f16x8 av = *(const f16x8*)(arow + j0);
            f16x8 hv;
#pragma unroll
            for (int jj = 0; jj < 8; ++jj) {
                int jc = j0 + jj;
                float v = (float)av[jj] + rx * s_warel[jc] + ry * s_warel[C + jc]
                        + rz * s_warel[2 * C + jc];
                hv[jj] = (f16)fmaxf(v, 0.0f);
            }
            *(f16x8*)(smem + e * (C * 2) + ((j0 * 2) ^ ((e & 7) << 4))) = hv;
        }
    }
    __syncthreads();

    // ---- phase 2: msg = h1 @ wb via MFMA (each wave: 64 rows x C/4 cols)
    const int w = tid >> 6, l = tid & 63, lr = l & 15, lg = l >> 4;
    f32x4 acc[4][NTW];
#pragma unroll
    for (int m = 0; m < 4; ++m)
#pragma unroll
        for (int nt = 0; nt < NTW; ++nt) {
            acc[m][nt][0] = 0.f; acc[m][nt][1] = 0.f;
            acc[m][nt][2] = 0.f; acc[m][nt][3] = 0.f;
        }
#pragma unroll
    for (int ks = 0; ks < KS; ++ks) {
        f16x8 af[4];
#pragma unroll
        for (int m = 0; m < 4; ++m) {
            const int row = m * 16 + lr;
            af[m] = *(const f16x8*)(smem + row * (C * 2)
                     + (((ks * 32 + lg * 8) * 2) ^ ((row & 7) << 4)));
        }
#pragma unroll
        for (int nt = 0; nt < NTW; ++nt) {
            const int ntg = w * NTW + nt;
            f16x8 bf = *(const f16x8*)(pB + ((size_t)(ntg * KS + ks) * 64 + l) * 8);
#pragma unroll
            for (int m = 0; m < 4; ++m)
                acc[m][nt] = __builtin_amdgcn_mfma_f32_16x16x32_f16(af[m], bf, acc[m][nt], 0, 0, 0);
        }
    }

    // ---- phases 3/4: spill msg in 32-row halves, segmented max, atomic flush
    float* msg = (float*)smem;
    const int c = tid;
    const bool active = (c < C);
    const float bbv = active ? bb[c] : 0.0f;
    float run = -INFINITY;
    int prev = s_dst[0];
#pragma unroll
    for (int half = 0; half < 2; ++half) {
        __syncthreads();   // previous smem use done
#pragma unroll
        for (int mi = 0; mi < 2; ++mi) {
            const int m = half * 2 + mi;
#pragma unroll
            for (int nt = 0; nt < NTW; ++nt) {
                const int col = w * (C / 4) + nt * 16 + lr;
#pragma unroll
                for (int rr = 0; rr < 4; ++rr) {
                    const int row = m * 16 + lg * 4 + rr;
                    msg[(row - half * 32) * C + col] = acc[m][nt][rr];
                }
            }
        }
        __syncthreads();
        if (active) {
            for (int e2 = 0; e2 < 32; ++e2) {
                const int d = s_dst[half * 32 + e2];
                const float v = msg[e2 * C + c];
                if (d != prev) {
                    atomic_max_f(&agg[(size_t)prev * C + c], run + bbv);
                    run = v; prev = d;
                } else {
                    run = fmaxf(run, v);
                }
            }
        }
    }
    if (active) atomic_max_f(&agg[(size_t)prev * C + c], run + bbv);
}

// ---------- projection: scatter-add features into (B,256,60,80) --------------
__global__ __launch_bounds__(256) void project(const float* __restrict__ feat, // N x 256
                                               const float* __restrict__ pos,
                                               const float* __restrict__ Km,
                                               const int* __restrict__ batch,
                                               float* __restrict__ out) {
    const int n = blockIdx.x;
    const float X = pos[3 * n + 0], Y = pos[3 * n + 1], Z = pos[3 * n + 2];
    const float k00 = Km[0], k02 = Km[2], k11 = Km[4], k12 = Km[5];
    const int u = (int)((k00 * X / Z + k02) / 640.0f * 80.0f);
    const int v = (int)((k11 * Y / Z + k12) / 480.0f * 60.0f);
    if (u < 0 || u >= 80 || v < 0 || v >= 60) return;
    const int b = batch[n];
    const int c = threadIdx.x;
    float val = feat[(size_t)n * 256 + c];
    if (!isfinite(val)) val = 0.0f;
    atomicAdd(out + (((size_t)b * 256 + c) * 60 + v) * 80 + u, val);
}

// ---------------------------------------------------------------------------
extern "C" void kernel_launch(void* const* d_in, const int* in_sizes, int n_in,
                              void* d_out, int out_size, void* d_ws, size_t ws_size,
                              hipStream_t stream) {
    const float* x   = (const float*)d_in[0];
    const float* pos = (const float*)d_in[1];
    const float* Km  = (const float*)d_in[2];
    const float* w11 = (const float*)d_in[3];
    const float* b11 = (const float*)d_in[4];
    const float* w12 = (const float*)d_in[5];
    const float* b12 = (const float*)d_in[6];
    const float* w21 = (const float*)d_in[7];
    const float* b21 = (const float*)d_in[8];
    const float* w22 = (const float*)d_in[9];
    const float* b22 = (const float*)d_in[10];
    const float* w31 = (const float*)d_in[11];
    const float* b31 = (const float*)d_in[12];
    const float* w32 = (const float*)d_in[13];
    const float* b32 = (const float*)d_in[14];
    const int* edge  = (const int*)d_in[15];
    const int* batch = (const int*)d_in[16];
    const int* srcp = edge;
    const int* dstp = edge + NE;
    float* out = (float*)d_out;

    // workspace layout (~80.4 MB)
    float* aggA  = (float*)d_ws;                      // N x 256 f32
    float* aggB  = aggA + (size_t)NN * 256;           // N x 256 f32
    f16*   Ah    = (f16*)(aggB + (size_t)NN * 256);   // N x 256 f16
    int*   srcS  = (int*)(Ah + (size_t)NN * 256);     // E
    int*   dstS  = srcS + NE;                         // E
    int*   counts = dstS + NE;                        // N
    int*   cursor = counts + NN;                      // N
    f16*   pW1   = (f16*)(cursor + NN);               // 64*64
    f16*   pW2   = pW1 + 64 * 64;                     // 128*128
    f16*   pW3   = pW2 + 128 * 128;                   // 256*256

    // ---- sort edges by dst (reused by all 3 layers)
    hipMemsetAsync(counts, 0, NN * sizeof(int), stream);
    hist_dst<<<(NE + 255) / 256, 256, 0, stream>>>(dstp, counts);
    scan_counts<<<1, 1024, 0, stream>>>(counts, cursor);
    scatter_edges<<<(NE + 255) / 256, 256, 0, stream>>>(srcp, dstp, cursor, srcS, dstS);

    // ---- pack wb weights to f16 fragment layout
    pack_wb<64><<<(64 * 64 + 255) / 256, 256, 0, stream>>>(w12, pW1);
    pack_wb<128><<<(128 * 128 + 255) / 256, 256, 0, stream>>>(w22, pW2);
    pack_wb<256><<<(256 * 256 + 255) / 256, 256, 0, stream>>>(w32, pW3);

    // ---- layer 1: cin=16, cout=64
    node_linear<16, 64><<<NN / 8, 256, 0, stream>>>(x, w11, b11, Ah);
    fill_neg_inf<<<512, 256, 0, stream>>>(aggB, NN * 64);
    edge_mfma<64><<<NE / 64, 256, 0, stream>>>(Ah, w11 + 16 * 64, pW1, b12,
                                               pos, srcS, dstS, aggB);
    // ---- layer 2: cin=64, cout=128
    node_linear<64, 128><<<NN / 8, 256, 0, stream>>>(aggB, w21, b21, Ah);
    fill_neg_inf<<<512, 256, 0, stream>>>(aggA, NN * 128);
    edge_mfma<128><<<NE / 64, 256, 0, stream>>>(Ah, w21 + 64 * 128, pW2, b22,
                                                pos, srcS, dstS, aggA);
    // ---- layer 3: cin=128, cout=256
    node_linear<128, 256><<<NN / 8, 256, 0, stream>>>(aggA, w31, b31, Ah);
    fill_neg_inf<<<512, 256, 0, stream>>>(aggB, NN * 256);
    edge_mfma<256><<<NE / 64, 256, 0, stream>>>(Ah, w31 + 128 * 256, pW3, b32,
                                                pos, srcS, dstS, aggB);
    // ---- projection
    hipMemsetAsync(d_out, 0, (size_t)out_size * sizeof(float), stream);
    project<<<NN, 256, 0, stream>>>(aggB, pos, Km, batch, out);
}

// Round 3
// 423.708 us; speedup vs baseline: 9.8535x; 1.8528x over previous
//
#include <hip/hip_runtime.h>
#include <math.h>

#define NN 30000
#define NE 400000

typedef _Float16 f16;
typedef _Float16 f16x8 __attribute__((ext_vector_type(8)));
typedef float f32x4 __attribute__((ext_vector_type(4)));

// ---------- float atomic max via int/uint atomics (valid incl. -inf init) ----
__device__ __forceinline__ void atomic_max_f(float* addr, float v) {
    if (v >= 0.0f) {
        atomicMax((int*)addr, __float_as_int(v));
    } else {
        atomicMin((unsigned int*)addr, __float_as_uint(v));
    }
}

__global__ __launch_bounds__(256) void fill_neg_inf(float* p, int n) {
    int i = blockIdx.x * blockDim.x + threadIdx.x;
    int stride = gridDim.x * blockDim.x;
    for (; i < n; i += stride) p[i] = -INFINITY;
}

// ---------- counting-sort of edges by dst --------------------------------
__global__ __launch_bounds__(256) void hist_dst(const int* __restrict__ dst,
                                                int* __restrict__ counts) {
    int e = blockIdx.x * 256 + threadIdx.x;
    if (e < NE) atomicAdd(&counts[dst[e]], 1);
}

__global__ __launch_bounds__(1024) void scan_counts(const int* __restrict__ counts,
                                                    int* __restrict__ cursor) {
    __shared__ int lsum[1024];
    const int t = threadIdx.x;
    const int base = t * 30;                 // 1024*30 = 30720 >= 30000
    int s = 0;
    for (int i = 0; i < 30; ++i) {
        int idx = base + i;
        if (idx < NN) s += counts[idx];
    }
    lsum[t] = s;
    __syncthreads();
    int acc = s;
    for (int off = 1; off < 1024; off <<= 1) {
        int v = (t >= off) ? lsum[t - off] : 0;
        __syncthreads();
        acc += v;
        lsum[t] = acc;
        __syncthreads();
    }
    int run = acc - s;                       // exclusive prefix
    for (int i = 0; i < 30; ++i) {
        int idx = base + i;
        if (idx < NN) { cursor[idx] = run; run += counts[idx]; }
    }
}

__global__ __launch_bounds__(256) void scatter_edges(const int* __restrict__ src,
                                                     const int* __restrict__ dst,
                                                     int* __restrict__ cursor,
                                                     int* __restrict__ srcS,
                                                     int* __restrict__ dstS) {
    int e = blockIdx.x * 256 + threadIdx.x;
    if (e >= NE) return;
    int d = dst[e];
    int p = atomicAdd(&cursor[d], 1);
    srcS[p] = src[e];
    dstS[p] = d;
}

// ---------- pack weight (fp32 row-major KxN) into MFMA b-frag order, f16 -----
// flat = ((nt*(K/32)+ks)*64 + lane)*8 + j ; k = ks*32 + (lane>>4)*8 + j ; n = nt*16 + (lane&15)
template<int K, int N>
__global__ __launch_bounds__(256) void pack_w(const float* __restrict__ wsrc,
                                              f16* __restrict__ pB) {
    int f = blockIdx.x * 256 + threadIdx.x;
    if (f >= K * N) return;
    int j = f & 7;
    int l = (f >> 3) & 63;
    int rest = f >> 9;
    constexpr int KS = K / 32;
    int ks = rest % KS;
    int nt = rest / KS;
    int k = ks * 32 + ((l >> 4) << 3) + j;
    int n = nt * 16 + (l & 15);
    pB[f] = (f16)wsrc[k * N + n];
}

// ---------- layer-1 node linear (K=16, tiny): scalar --------------------------
template<int K, int COUT>
__global__ __launch_bounds__(256) void node_linear(const float* __restrict__ feat,
                                                   const float* __restrict__ wa,
                                                   const float* __restrict__ b,
                                                   f16* __restrict__ A) {
    constexpr int NPB = 8;
    constexpr int G   = 256 / COUT;
    constexpr int NPT = NPB / G;
    __shared__ float sf[NPB * K];
    const int node0 = blockIdx.x * NPB;
    for (int idx = threadIdx.x; idx < NPB * K; idx += 256) {
        float v = feat[node0 * K + idx];
        if (!isfinite(v)) v = 0.0f;
        sf[idx] = v;
    }
    __syncthreads();
    const int j  = threadIdx.x % COUT;
    const int g  = threadIdx.x / COUT;
    const int n0 = g * NPT;
    float acc[NPT];
#pragma unroll
    for (int i = 0; i < NPT; i++) acc[i] = 0.0f;
    for (int k = 0; k < K; k++) {
        float w = wa[k * COUT + j];
#pragma unroll
        for (int nn = 0; nn < NPT; nn++)
            acc[nn] = fmaf(sf[(n0 + nn) * K + k], w, acc[nn]);
    }
    const float bj = b[j];
#pragma unroll
    for (int nn = 0; nn < NPT; nn++)
        A[(size_t)(node0 + n0 + nn) * COUT + j] = (f16)(acc[nn] + bj);
}

// ---------- node GEMM via MFMA: A[n][C] = fixup(feat[n][K]) @ wa + bias -> f16
template<int K, int C>
__global__ __launch_bounds__(256) void node_gemm(const float* __restrict__ feat,
                                                 const f16* __restrict__ pW,
                                                 const float* __restrict__ bias,
                                                 f16* __restrict__ A) {
    constexpr int NTW = C / 64;   // n-tiles per wave
    constexpr int KS  = K / 32;   // k-steps
    __shared__ __align__(16) unsigned char smem[64 * K * 2];
    const int tid = threadIdx.x;
    const int node0 = blockIdx.x * 64;

    // stage 64 node rows (f32 -> f16, isfinite fixup, XOR-swizzled)
    {
        const int e = tid >> 2, p = tid & 3;
        const bool valid = (node0 + e) < NN;
        const float* frow = feat + (size_t)(node0 + e) * K;
#pragma unroll
        for (int ch = 0; ch < K / 32; ++ch) {
            const int j0 = (ch * 4 + p) * 8;
            f16x8 hv;
#pragma unroll
            for (int jj = 0; jj < 8; ++jj) {
                float v = valid ? frow[j0 + jj] : 0.0f;
                if (!isfinite(v)) v = 0.0f;
                hv[jj] = (f16)v;
            }
            *(f16x8*)(smem + e * (K * 2) + ((j0 * 2) ^ ((e & 7) << 4))) = hv;
        }
    }
    __syncthreads();

    const int w = tid >> 6, l = tid & 63, lr = l & 15, lg = l >> 4;
    f32x4 acc[4][NTW];
#pragma unroll
    for (int m = 0; m < 4; ++m)
#pragma unroll
        for (int nt = 0; nt < NTW; ++nt) {
            acc[m][nt][0] = 0.f; acc[m][nt][1] = 0.f;
            acc[m][nt][2] = 0.f; acc[m][nt][3] = 0.f;
        }
#pragma unroll
    for (int ks = 0; ks < KS; ++ks) {
        f16x8 af[4];
#pragma unroll
        for (int m = 0; m < 4; ++m) {
            const int row = m * 16 + lr;
            af[m] = *(const f16x8*)(smem + row * (K * 2)
                     + (((ks * 32 + lg * 8) * 2) ^ ((row & 7) << 4)));
        }
#pragma unroll
        for (int nt = 0; nt < NTW; ++nt) {
            const int ntg = w * NTW + nt;
            f16x8 bf = *(const f16x8*)(pW + ((size_t)(ntg * KS + ks) * 64 + l) * 8);
#pragma unroll
            for (int m = 0; m < 4; ++m)
                acc[m][nt] = __builtin_amdgcn_mfma_f32_16x16x32_f16(af[m], bf, acc[m][nt], 0, 0, 0);
        }
    }
    // epilogue: + bias, f16 store
#pragma unroll
    for (int m = 0; m < 4; ++m)
#pragma unroll
        for (int nt = 0; nt < NTW; ++nt) {
            const int col = w * (C / 4) + nt * 16 + lr;
            const float bv = bias[col];
#pragma unroll
            for (int rr = 0; rr < 4; ++rr) {
                const int row = m * 16 + lg * 4 + rr;
                if (node0 + row < NN)
                    A[(size_t)(node0 + row) * C + col] = (f16)(acc[m][nt][rr] + bv);
            }
        }
}

// ---------- edge kernel: h1=relu(Ah[src]+rel@warel) ; msg=h1@wb ;
//            in-LDS segmented max over dst-sorted edges ; atomic_max(+bb) -----
template<int C>
__global__ __launch_bounds__(256) void edge_mfma(const f16* __restrict__ Ah,
                                                 const float* __restrict__ warel, // 3 x C fp32
                                                 const f16* __restrict__ pB,      // packed
                                                 const float* __restrict__ bb,
                                                 const float* __restrict__ pos,
                                                 const int* __restrict__ srcS,
                                                 const int* __restrict__ dstS,
                                                 float* __restrict__ agg) {
    constexpr int TE  = 64;
    constexpr int NTW = C / 64;   // n-tiles per wave
    constexpr int KS  = C / 32;   // k-steps
    __shared__ __align__(16) unsigned char smem[TE * C * 2];
    __shared__ float s_warel[3 * C];
    __shared__ float s_rx[TE], s_ry[TE], s_rz[TE];
    __shared__ int s_src[TE], s_dst[TE];

    const int tid = threadIdx.x;
    const int nwg = gridDim.x;
    const int q = nwg >> 3, r = nwg & 7;
    const int xcd = blockIdx.x & 7, o = blockIdx.x >> 3;
    const int bid = (xcd < r ? xcd * (q + 1) : r * (q + 1) + (xcd - r) * q) + o;
    const int e0 = bid * TE;

    if (tid < TE) {
        int s = srcS[e0 + tid], d = dstS[e0 + tid];
        s_src[tid] = s; s_dst[tid] = d;
        s_rx[tid] = pos[3 * s + 0] - pos[3 * d + 0];
        s_ry[tid] = pos[3 * s + 1] - pos[3 * d + 1];
        s_rz[tid] = pos[3 * s + 2] - pos[3 * d + 2];
    }
    for (int i = tid; i < 3 * C; i += 256) s_warel[i] = warel[i];
    __syncthreads();

    // ---- phase 1: h1 into LDS (f16, XOR-swizzled rows)
    {
        const int e = tid >> 2, p = tid & 3;
        const int s = s_src[e];
        const float rx = s_rx[e], ry = s_ry[e], rz = s_rz[e];
        const f16* arow = Ah + (size_t)s * C;
#pragma unroll
        for (int ch = 0; ch < C / 32; ++ch) {
            const int j0 = (ch * 4 + p) * 8;
            f16x8 av = *(const f16x8*)(arow + j0);
            f16x8 hv;
#pragma unroll
            for (int jj = 0; jj < 8; ++jj) {
                int jc = j0 + jj;
                float v = (float)av[jj] + rx * s_warel[jc] + ry * s_warel[C + jc]
                        + rz * s_warel[2 * C + jc];
                hv[jj] = (f16)fmaxf(v, 0.0f);
            }
            *(f16x8*)(smem + e * (C * 2) + ((j0 * 2) ^ ((e & 7) << 4))) = hv;
        }
    }
    __syncthreads();

    // ---- phase 2: msg = h1 @ wb via MFMA (each wave: 64 rows x C/4 cols)
    const int w = tid >> 6, l = tid & 63, lr = l & 15, lg = l >> 4;
    f32x4 acc[4][NTW];
#pragma unroll
    for (int m = 0; m < 4; ++m)
#pragma unroll
        for (int nt = 0; nt < NTW; ++nt) {
            acc[m][nt][0] = 0.f; acc[m][nt][1] = 0.f;
            acc[m][nt][2] = 0.f; acc[m][nt][3] = 0.f;
        }
#pragma unroll
    for (int ks = 0; ks < KS; ++ks) {
        f16x8 af[4];
#pragma unroll
        for (int m = 0; m < 4; ++m) {
            const int row = m * 16 + lr;
            af[m] = *(const f16x8*)(smem + row * (C * 2)
                     + (((ks * 32 + lg * 8) * 2) ^ ((row & 7) << 4)));
        }
#pragma unroll
        for (int nt = 0; nt < NTW; ++nt) {
            const int ntg = w * NTW + nt;
            f16x8 bf = *(const f16x8*)(pB + ((size_t)(ntg * KS + ks) * 64 + l) * 8);
#pragma unroll
            for (int m = 0; m < 4; ++m)
                acc[m][nt] = __builtin_amdgcn_mfma_f32_16x16x32_f16(af[m], bf, acc[m][nt], 0, 0, 0);
        }
    }

    // ---- phases 3/4: spill msg in 32-row halves, segmented max, atomic flush
    float* msg = (float*)smem;
    const int c = tid;
    const bool active = (c < C);
    const float bbv = active ? bb[c] : 0.0f;
    float run = -INFINITY;
    int prev = s_dst[0];
#pragma unroll
    for (int half = 0; half < 2; ++half) {
        __syncthreads();
#pragma unroll
        for (int mi = 0; mi < 2; ++mi) {
            const int m = half * 2 + mi;
#pragma unroll
            for (int nt = 0; nt < NTW; ++nt) {
                const int col = w * (C / 4) + nt * 16 + lr;
#pragma unroll
                for (int rr = 0; rr < 4; ++rr) {
                    const int row = m * 16 + lg * 4 + rr;
                    msg[(row - half * 32) * C + col] = acc[m][nt][rr];
                }
            }
        }
        __syncthreads();
        if (active) {
            for (int e2 = 0; e2 < 32; ++e2) {
                const int d = s_dst[half * 32 + e2];
                const float v = msg[e2 * C + c];
                if (d != prev) {
                    atomic_max_f(&agg[(size_t)prev * C + c], run + bbv);
                    run = v; prev = d;
                } else {
                    run = fmaxf(run, v);
                }
            }
        }
    }
    if (active) atomic_max_f(&agg[(size_t)prev * C + c], run + bbv);
}

// ---------- projection step 1: coalesced atomic scatter into pixel-major img -
__global__ __launch_bounds__(256) void scatter_img(const float* __restrict__ feat, // N x 256
                                                   const float* __restrict__ pos,
                                                   const float* __restrict__ Km,
                                                   const int* __restrict__ batch,
                                                   float* __restrict__ img) {  // [B*4800][256]
    const int n = blockIdx.x;
    const float X = pos[3 * n + 0], Y = pos[3 * n + 1], Z = pos[3 * n + 2];
    const float k00 = Km[0], k02 = Km[2], k11 = Km[4], k12 = Km[5];
    const int u = (int)((k00 * X / Z + k02) / 640.0f * 80.0f);
    const int v = (int)((k11 * Y / Z + k12) / 480.0f * 60.0f);
    if (u < 0 || u >= 80 || v < 0 || v >= 60) return;
    const int p = (batch[n] * 60 + v) * 80 + u;
    const int c = threadIdx.x;
    float val = feat[(size_t)n * 256 + c];
    if (!isfinite(val)) val = 0.0f;
    atomicAdd(img + (size_t)p * 256 + c, val);
}

// ---------- projection step 2: tiled transpose img[b][p][c] -> out[b][c][p] --
__global__ __launch_bounds__(256) void transpose_img(const float* __restrict__ img,
                                                     float* __restrict__ out) {
    __shared__ float tile[32][33];
    const int b = blockIdx.z;
    const int p0 = blockIdx.x * 32, c0 = blockIdx.y * 32;
    const float* src = img + (size_t)b * 4800 * 256;
    float* dst = out + (size_t)b * 256 * 4800;
    const int tx = threadIdx.x & 31, ty = threadIdx.x >> 5;  // 32 x 8
#pragma unroll
    for (int i = 0; i < 32; i += 8)
        tile[ty + i][tx] = src[(size_t)(p0 + ty + i) * 256 + c0 + tx];
    __syncthreads();
#pragma unroll
    for (int i = 0; i < 32; i += 8)
        dst[(size_t)(c0 + ty + i) * 4800 + p0 + tx] = tile[tx][ty + i];
}

// ---------------------------------------------------------------------------
extern "C" void kernel_launch(void* const* d_in, const int* in_sizes, int n_in,
                              void* d_out, int out_size, void* d_ws, size_t ws_size,
                              hipStream_t stream) {
    const float* x   = (const float*)d_in[0];
    const float* pos = (const float*)d_in[1];
    const float* Km  = (const float*)d_in[2];
    const float* w11 = (const float*)d_in[3];
    const float* b11 = (const float*)d_in[4];
    const float* w12 = (const float*)d_in[5];
    const float* b12 = (const float*)d_in[6];
    const float* w21 = (const float*)d_in[7];
    const float* b21 = (const float*)d_in[8];
    const float* w22 = (const float*)d_in[9];
    const float* b22 = (const float*)d_in[10];
    const float* w31 = (const float*)d_in[11];
    const float* b31 = (const float*)d_in[12];
    const float* w32 = (const float*)d_in[13];
    const float* b32 = (const float*)d_in[14];
    const int* edge  = (const int*)d_in[15];
    const int* batch = (const int*)d_in[16];
    const int* srcp = edge;
    const int* dstp = edge + NE;
    float* out = (float*)d_out;

    // workspace layout (~80.5 MB)
    float* aggA  = (float*)d_ws;                      // N x 256 f32 (also img: 4*4800*256 f32)
    float* aggB  = aggA + (size_t)NN * 256;           // N x 256 f32
    f16*   Ah    = (f16*)(aggB + (size_t)NN * 256);   // N x 256 f16
    int*   srcS  = (int*)(Ah + (size_t)NN * 256);     // E
    int*   dstS  = srcS + NE;                         // E
    int*   counts = dstS + NE;                        // N
    int*   cursor = counts + NN;                      // N
    f16*   pW1   = (f16*)(cursor + NN);               // 64*64
    f16*   pW2   = pW1 + 64 * 64;                     // 128*128
    f16*   pW3   = pW2 + 128 * 128;                   // 256*256
    f16*   pW2n  = pW3 + 256 * 256;                   // 64*128  (node L2)
    f16*   pW3n  = pW2n + 64 * 128;                   // 128*256 (node L3)

    // ---- sort edges by dst (reused by all 3 layers)
    hipMemsetAsync(counts, 0, NN * sizeof(int), stream);
    hist_dst<<<(NE + 255) / 256, 256, 0, stream>>>(dstp, counts);
    scan_counts<<<1, 1024, 0, stream>>>(counts, cursor);
    scatter_edges<<<(NE + 255) / 256, 256, 0, stream>>>(srcp, dstp, cursor, srcS, dstS);

    // ---- pack weights to f16 fragment layout
    pack_w<64, 64><<<(64 * 64 + 255) / 256, 256, 0, stream>>>(w12, pW1);
    pack_w<128, 128><<<(128 * 128 + 255) / 256, 256, 0, stream>>>(w22, pW2);
    pack_w<256, 256><<<(256 * 256 + 255) / 256, 256, 0, stream>>>(w32, pW3);
    pack_w<64, 128><<<(64 * 128 + 255) / 256, 256, 0, stream>>>(w21, pW2n);
    pack_w<128, 256><<<(128 * 256 + 255) / 256, 256, 0, stream>>>(w31, pW3n);

    // ---- layer 1: cin=16, cout=64
    node_linear<16, 64><<<NN / 8, 256, 0, stream>>>(x, w11, b11, Ah);
    fill_neg_inf<<<512, 256, 0, stream>>>(aggB, NN * 64);
    edge_mfma<64><<<NE / 64, 256, 0, stream>>>(Ah, w11 + 16 * 64, pW1, b12,
                                               pos, srcS, dstS, aggB);
    // ---- layer 2: cin=64, cout=128
    node_gemm<64, 128><<<(NN + 63) / 64, 256, 0, stream>>>(aggB, pW2n, b21, Ah);
    fill_neg_inf<<<512, 256, 0, stream>>>(aggA, NN * 128);
    edge_mfma<128><<<NE / 64, 256, 0, stream>>>(Ah, w21 + 64 * 128, pW2, b22,
                                                pos, srcS, dstS, aggA);
    // ---- layer 3: cin=128, cout=256
    node_gemm<128, 256><<<(NN + 63) / 64, 256, 0, stream>>>(aggA, pW3n, b31, Ah);
    fill_neg_inf<<<512, 256, 0, stream>>>(aggB, NN * 256);
    edge_mfma<256><<<NE / 64, 256, 0, stream>>>(Ah, w31 + 128 * 256, pW3, b32,
                                                pos, srcS, dstS, aggB);
    // ---- projection: coalesced scatter into pixel-major img, then transpose
    hipMemsetAsync(aggA, 0, (size_t)4 * 4800 * 256 * sizeof(float), stream);
    scatter_img<<<NN, 256, 0, stream>>>(aggB, pos, Km, batch, aggA);
    transpose_img<<<dim3(150, 8, 4), 256, 0, stream>>>(aggA, out);
}